// Round 6
// baseline (606.224 us; speedup 1.0000x reference)
//
#include <hip/hip_runtime.h>
#include <math.h>

#define CIN   3
#define DIN   16
#define HWIN  64
#define COUT  24
#define DOUT  14
#define HOUT  62
#define WOUT  62

#define TILE_H  4
#define NTILES  16                      // 62 rows -> 16 tiles of 4 (last 2 rows masked)
#define NTHR    384                     // 6 waves; wave q owns co = 4q..4q+3
#define ROWS_IN 6                       // input rows per tile
#define RP      68                      // padded x row (floats)
#define PLANE_F (CIN * ROWS_IN * RP)    // 1224 floats per depth plane
#define XSLAB_F (DIN * PLANE_F)         // 19584 floats = 78336 B (x slab ONLY in LDS)
#define WQ_F    324                     // ws floats per co-quad: [g][tap][co&3]
#define SM_RP     64
#define SM_STRIDE (TILE_H * SM_RP)      // 256; sm overlays the x slab after the loop

// x: [128][3][16][64][64]  w: [24][3][3][3][3]  out: softmax_co(min_dz(conv+bias))
//
// v8 vs v7 (DS-pipe-bound 2.3x: x-reads 8.3K + weight-b128 3.9K cy/wave vs 6.8K budget):
//  - weights OFF the DS pipe: repacked into d_ws (kernel 1), loaded per combo at a
//    wave-uniform global address -> s_load / L1 (zero DS cycles).
//  - co/wave 3 -> 4 (6 waves): FMA per x-pair 36 -> 48, DS budget 9.07K >= x 8.9K.
//  - LDS = 78.3KB x-slab only -> 2 blocks/CU, 12 waves, 3/SIMD.
//  - chunks 3,3,3,3,2: acc[C][4][4] <= 48 regs, ~118 live -> no spills at 128 cap.

__device__ __forceinline__ void gload_lds_dw(const float* g, float* l) {
    __builtin_amdgcn_global_load_lds(
        (const __attribute__((address_space(1))) unsigned int*)g,
        (__attribute__((address_space(3))) unsigned int*)l, 4, 0, 0);
}

__global__ void repack_weights_v8(const float* __restrict__ w, float* __restrict__ ws) {
    const int i = threadIdx.x + blockIdx.x * blockDim.x;
    if (i < COUT * 81) {
        const int co   = i / 81;
        const int rem  = i % 81;
        const int cin  = rem / 27;
        const int rem2 = rem % 27;
        const int kd   = rem2 / 9;
        const int kh   = (rem2 % 9) / 3;
        const int kw   = rem2 % 3;
        // [quad][g=cin*3+kh][tap=kd*3+kw][co&3]
        ws[(co >> 2) * WQ_F + (cin * 3 + kh) * 36 + (kd * 3 + kw) * 4 + (co & 3)] = w[i];
    }
}

template<int C>
__device__ __forceinline__ void do_chunk(const float* __restrict__ xv,   // smem + vbase
                                         const float* __restrict__ wsq, // ws + quad*WQ_F (uniform)
                                         float (&m)[4][4], const int p0)
{
    float acc[C][4][4];
    #pragma unroll
    for (int d = 0; d < C; ++d)
        #pragma unroll
        for (int cop = 0; cop < 4; ++cop)
            #pragma unroll
            for (int i = 0; i < 4; ++i) acc[d][cop][i] = 0.f;

    #pragma unroll 1
    for (int cin = 0; cin < CIN; ++cin) {
        #pragma unroll 1
        for (int kh = 0; kh < 3; ++kh) {
            const float* __restrict__ bp = xv + p0 * PLANE_F + cin * (ROWS_IN * RP) + kh * RP;
            const int g = cin * 3 + kh;

            // 9 taps x 4 co from GLOBAL workspace (uniform addr -> scalar/L1, no DS)
            float4 wv[9];
            #pragma unroll
            for (int t = 0; t < 9; ++t)
                wv[t] = *(const float4*)(wsq + g * 36 + t * 4);

            #pragma unroll
            for (int pp = 0; pp < C + 2; ++pp) {   // sweep planes: x row read ONCE
                const float* rp2 = bp + pp * PLANE_F;
                const float4 a4 = *(const float4*)rp2;        // ds_read_b128
                const float2 a2 = *(const float2*)(rp2 + 4);  // ds_read_b64
                const float xr[6] = { a4.x, a4.y, a4.z, a4.w, a2.x, a2.y };
                #pragma unroll
                for (int kd = 0; kd < 3; ++kd) {
                    const int d = pp - kd;
                    if (d < 0 || d >= C) continue;            // compile-time pruned
                    #pragma unroll
                    for (int kw = 0; kw < 3; ++kw) {
                        const float4 wt = wv[kd * 3 + kw];
                        const float wc[4] = { wt.x, wt.y, wt.z, wt.w };
                        #pragma unroll
                        for (int cop = 0; cop < 4; ++cop)
                            #pragma unroll
                            for (int i = 0; i < 4; ++i)
                                acc[d][cop][i] = fmaf(wc[cop], xr[i + kw], acc[d][cop][i]);
                    }
                }
            }
        }
    }

    #pragma unroll
    for (int d = 0; d < C; ++d)
        #pragma unroll
        for (int cop = 0; cop < 4; ++cop)
            #pragma unroll
            for (int i = 0; i < 4; ++i)
                m[cop][i] = fminf(m[cop][i], acc[d][cop][i]);
}

__global__ __launch_bounds__(NTHR, 3) void conv_min_softmax_v8(
    const float* __restrict__ x,
    const float* __restrict__ ws,
    const float* __restrict__ bias,
    float* __restrict__ out)
{
    __shared__ __align__(16) float smem[XSLAB_F];

    const int tid  = threadIdx.x;
    const int bid  = blockIdx.x;
    const int rt   = bid & (NTILES - 1);
    const int b    = bid >> 4;

    const int q    = __builtin_amdgcn_readfirstlane(tid >> 6);  // wave id 0..5 (uniform)
    const int lane = tid & 63;
    const int r    = lane >> 4;          // 0..3 output row in tile
    const int wg   = lane & 15;          // 0..15 -> wo = 4*wg..4*wg+3
    const int q4   = q * 4;

    const float bia[4] = { bias[q4 + 0], bias[q4 + 1], bias[q4 + 2], bias[q4 + 3] };

    // ---- stage ALL 16 planes via global_load_lds: 288 rows, 48 per wave
    {
        const float* __restrict__ xb =
            x + (size_t)b * (CIN * DIN * HWIN * HWIN) + lane;
        #pragma unroll 1
        for (int k = 0; k < 48; ++k) {
            const int j    = q * 48 + k;         // 0..287
            const int p    = j / 18;             // plane
            const int sub  = j % 18;
            const int cin  = sub / 6;
            const int row  = sub % 6;
            const int grow = min(rt * TILE_H + row, HWIN - 1);   // clamp last tile
            gload_lds_dw(xb + ((cin * DIN + p) * (HWIN * HWIN) + grow * HWIN),
                         &smem[p * PLANE_F + (cin * ROWS_IN + row) * RP]);
        }
    }
    __syncthreads();   // drains global_load_lds; the ONLY main barrier

    float m[4][4];
    #pragma unroll
    for (int cop = 0; cop < 4; ++cop)
        #pragma unroll
        for (int i = 0; i < 4; ++i) m[cop][i] = 1e30f;

    const float* __restrict__ xv  = &smem[r * RP + wg * 4];
    const float* __restrict__ wsq = ws + q * WQ_F;               // uniform

    // dz chunks: [0,3) [3,6) [6,9) [9,12) [12,14)
    do_chunk<3>(xv, wsq, m, 0);
    do_chunk<3>(xv, wsq, m, 3);
    do_chunk<3>(xv, wsq, m, 6);
    do_chunk<3>(xv, wsq, m, 9);
    do_chunk<2>(xv, wsq, m, 12);

    __syncthreads();      // x slab dead; reuse smem as 24-channel min matrix

    {
        const int p = r * SM_RP + wg * 4;
        #pragma unroll
        for (int cop = 0; cop < 4; ++cop) {
            float4 v = { m[cop][0] + bia[cop], m[cop][1] + bia[cop],
                         m[cop][2] + bia[cop], m[cop][3] + bia[cop] };
            *(float4*)&smem[(q4 + cop) * SM_STRIDE + p] = v;
        }
    }
    __syncthreads();

    if (tid < 256) {                      // 4 rows x 64 cols, one pixel per thread
        const int row = tid >> 6;
        const int col = tid & 63;
        const int ho  = rt * TILE_H + row;
        if (col < WOUT && ho < HOUT) {
            float v[COUT];
            float mx = -1e30f;
            #pragma unroll
            for (int c = 0; c < COUT; ++c) {
                v[c] = smem[c * SM_STRIDE + row * SM_RP + col];
                mx = fmaxf(mx, v[c]);
            }
            float s = 0.f;
            #pragma unroll
            for (int c = 0; c < COUT; ++c) { v[c] = __expf(v[c] - mx); s += v[c]; }
            const float inv = 1.f / s;
            float* ob = out + (size_t)b * COUT * (HOUT * WOUT) + ho * WOUT + col;
            #pragma unroll
            for (int c = 0; c < COUT; ++c)
                ob[(size_t)c * (HOUT * WOUT)] = v[c] * inv;
        }
    }
}

extern "C" void kernel_launch(void* const* d_in, const int* in_sizes, int n_in,
                              void* d_out, int out_size, void* d_ws, size_t ws_size,
                              hipStream_t stream) {
    const float* x    = (const float*)d_in[0];
    const float* w    = (const float*)d_in[1];
    const float* bias = (const float*)d_in[2];
    float* out = (float*)d_out;
    float* ws  = (float*)d_ws;

    repack_weights_v8<<<8, 256, 0, stream>>>(w, ws);
    conv_min_softmax_v8<<<128 * NTILES, NTHR, 0, stream>>>(x, ws, bias, out);
}